// Round 3
// baseline (280.447 us; speedup 1.0000x reference)
//
#include <hip/hip_runtime.h>
#include <math.h>

// CenterNetDecode fused: heat [8,80,192,192] f32, box [8,4,192,192] f32
// outputs (flat concat): boxes [B,H,W,4], mask [B,H,W], scores [B,H,W], center [B,H,W,2]
//
// Single kernel, 512 threads = 8 waves (round-1 structure: float4 / 48 lanes,
// 256-VGPR budget -> no scratch spill; round-2's 1024-thr float3 variant
// spilled v[] to scratch: WRITE_SIZE 135 MB vs 9.4 ideal).
// Block = one SS=6 row-strip of one image, all 80 channels (8 waves x 10 ch).
// NEW: 2-deep software pipeline on the channel loop — issue channel k+1's
// 8 float4 loads before computing channel k, so HBM latency (~900 cy) hides
// under the ~360-cy NMS compute instead of being exposed every iteration.
// Grid 32x8 = 256 blocks = exactly 1 block/CU.

#define BB 8
#define CC 80
#define HH 192
#define WW 192
#define SS 6                 // rows per block strip  (HH/SS = 32 strips)
#define NPIX (SS*WW)         // 1152 pixels per block
#define NBPIX (BB*HH*WW)     // 294912
#define NT 512
#define NW (NT/64)           // 8 waves
#define CPW (CC/NW)          // 10 channels per wave

__global__ __launch_bounds__(NT) void fused_kernel(const float* __restrict__ heat,
                                                   const float* __restrict__ box,
                                                   float* __restrict__ out) {
    const int tid  = threadIdx.x;
    const int lane = tid & 63;
    const int wv   = tid >> 6;        // wave 0..7
    const int yt   = blockIdx.x;      // 0..31
    const int b    = blockIdx.y;      // 0..7
    const int y0   = yt * SS;
    const bool lok = lane < 48;
    const int  col0 = lane * 4;

    __shared__ float red[NW][SS][WW]; // 36 KB

    float4 sc[SS];
#pragma unroll
    for (int i = 0; i < SS; ++i) sc[i] = make_float4(0.f, 0.f, 0.f, 0.f);

    const int cbase = wv * CPW;
    const float NI = -INFINITY;

    // channel load: 8 rows (strip + vertical halo) of float4 per lane
#define LOADCH(V, CH) {                                                        \
        const float* hp = heat + ((size_t)(b * CC + (CH)) * HH) * WW;          \
        _Pragma("unroll")                                                      \
        for (int r = 0; r < SS + 2; ++r) {                                     \
            const int  row = y0 - 1 + r;                                       \
            const bool ok  = lok && ((unsigned)row < HH);                      \
            V[r] = ok ? *reinterpret_cast<const float4*>(hp + row * WW + col0) \
                      : make_float4(NI, NI, NI, NI);                           \
        } }

    // 3x3 NMS + running channel-max into sc
#define COMPUTECH(V) {                                                         \
        _Pragma("unroll")                                                      \
        for (int i = 0; i < SS; ++i) {                                         \
            const float4 a = V[i], m = V[i + 1], d = V[i + 2];                 \
            float4 vm;                                                         \
            vm.x = fmaxf(fmaxf(a.x, m.x), d.x);                                \
            vm.y = fmaxf(fmaxf(a.y, m.y), d.y);                                \
            vm.z = fmaxf(fmaxf(a.z, m.z), d.z);                                \
            vm.w = fmaxf(fmaxf(a.w, m.w), d.w);                                \
            float L = __shfl_up(vm.w, 1);                                      \
            float R = __shfl_down(vm.x, 1);                                    \
            if (lane == 0)  L = NI;                                            \
            if (lane >= 47) R = NI;                                            \
            float4 hm;                                                         \
            hm.x = fmaxf(fmaxf(L,    vm.x), vm.y);                             \
            hm.y = fmaxf(fmaxf(vm.x, vm.y), vm.z);                             \
            hm.z = fmaxf(fmaxf(vm.y, vm.z), vm.w);                             \
            hm.w = fmaxf(fmaxf(vm.z, vm.w), R);                                \
            sc[i].x = fmaxf(sc[i].x, (m.x == hm.x) ? m.x : 0.0f);              \
            sc[i].y = fmaxf(sc[i].y, (m.y == hm.y) ? m.y : 0.0f);              \
            sc[i].z = fmaxf(sc[i].z, (m.z == hm.z) ? m.z : 0.0f);              \
            sc[i].w = fmaxf(sc[i].w, (m.w == hm.w) ? m.w : 0.0f);              \
        } }

    float4 va[SS + 2], vb[SS + 2];
    LOADCH(va, cbase);                       // prologue: channel 0 in flight
#pragma unroll
    for (int k = 0; k < CPW; k += 2) {       // CPW=10, even
        LOADCH(vb, cbase + k + 1);           // issue k+1 while k computes
        COMPUTECH(va);
        if (k + 2 < CPW) LOADCH(va, cbase + k + 2);  // issue k+2 while k+1 computes
        COMPUTECH(vb);
    }

    // ---- decode prefetch: issue box loads BEFORE the barrier (latency hides
    //      under barrier + LDS reduce). Strip is linear: pix = pixbase + idx.
    const int    pixbase = (b * HH + y0) * WW;
    const float* bp0     = box + (size_t)b * 4 * HH * WW + (size_t)y0 * WW;
    float pdx[3], pdy[3], pw[3], ph[3];
#pragma unroll
    for (int kk = 0; kk < 3; ++kk) {
        const int idx = kk * NT + tid;
        if (idx < NPIX) {
            pdx[kk] = bp0[idx];
            pdy[kk] = bp0[idx + (size_t)HH * WW];
            pw[kk]  = bp0[idx + (size_t)2 * HH * WW];
            ph[kk]  = bp0[idx + (size_t)3 * HH * WW];
        }
    }

    if (lok) {
#pragma unroll
        for (int i = 0; i < SS; ++i)
            *reinterpret_cast<float4*>(&red[wv][i][col0]) = sc[i];
    }
    __syncthreads();

    float* boxes  = out;
    float* maskp  = out + (size_t)4 * NBPIX;
    float* scorep = out + (size_t)5 * NBPIX;
    float* ctr    = out + (size_t)6 * NBPIX;

    const float* rf = &red[0][0][0];      // linear view: rf[w*NPIX + idx]

#pragma unroll
    for (int kk = 0; kk < 3; ++kk) {
        const int idx = kk * NT + tid;
        if (idx < NPIX) {
            const int row = idx / WW;
            const int x   = idx - row * WW;
            const int y   = y0 + row;

            float s = rf[idx];
#pragma unroll
            for (int w = 1; w < NW; ++w) s = fmaxf(s, rf[w * NPIX + idx]);
            const bool m = s > 0.7f;

            const float cx = ((float)x + pdx[kk]) * 4.0f;
            const float cy = ((float)y + pdy[kk]) * 4.0f;
            const float w4 = pw[kk] * 4.0f;
            const float h4 = ph[kk] * 4.0f;
            const float lim = 768.0f;
            const float x1 = fminf(fmaxf(cx - w4 * 0.5f, 0.0f), lim);
            const float y1 = fminf(fmaxf(cy - h4 * 0.5f, 0.0f), lim);
            const float x2 = fminf(fmaxf(cx + w4 * 0.5f, 0.0f), lim);
            const float y2 = fminf(fmaxf(cy + h4 * 0.5f, 0.0f), lim);

            const int pix = pixbase + idx;

            float4 bo;
            bo.x = m ? x1 : 0.0f;
            bo.y = m ? y1 : 0.0f;
            bo.z = m ? (x2 - x1) : 0.0f;
            bo.w = m ? (y2 - y1) : 0.0f;
            reinterpret_cast<float4*>(boxes)[pix] = bo;

            maskp[pix]  = m ? 1.0f : 0.0f;
            scorep[pix] = m ? s : 0.0f;

            float2 cc;
            cc.x = m ? cx : 0.0f;
            cc.y = m ? cy : 0.0f;
            reinterpret_cast<float2*>(ctr)[pix] = cc;
        }
    }
}

extern "C" void kernel_launch(void* const* d_in, const int* in_sizes, int n_in,
                              void* d_out, int out_size, void* d_ws, size_t ws_size,
                              hipStream_t stream) {
    const float* heat = (const float*)d_in[0];
    const float* box  = (const float*)d_in[1];
    float* out = (float*)d_out;

    dim3 g(HH / SS, BB);              // 32 x 8 = 256 blocks, 1 per CU
    fused_kernel<<<g, NT, 0, stream>>>(heat, box, out);
}

// Round 4
// 276.067 us; speedup vs baseline: 1.0159x; 1.0159x over previous
//
#include <hip/hip_runtime.h>
#include <math.h>

// CenterNetDecode fused: heat [8,80,192,192] f32, box [8,4,192,192] f32
// outputs (flat concat): boxes [B,H,W,4], mask [B,H,W], scores [B,H,W], center [B,H,W,2]
//
// Single kernel, 512 threads = 8 waves, float4 / 48-lane row layout.
// Block = one SS=6 row-strip of one image, all 80 channels (8 waves x 10 ch).
// 2-deep software pipeline on the channel loop (issue k+1's 8 float4 loads
// before computing k) so HBM latency hides under NMS compute.
//
// __launch_bounds__(512, 2): grid is 256 blocks = 1 block/CU = 2 waves/SIMD
// REGARDLESS of VGPR count, so declare exactly that and unlock the 256-VGPR
// budget. Round-3's bare __launch_bounds__(512) let the compiler cap at 128
// VGPRs (chasing 4 waves/EU the grid can never have) and spilled the entire
// va/vb pipeline to scratch: WRITE_SIZE 191.7 MB vs 9.4 ideal, kernel 182us.

#define BB 8
#define CC 80
#define HH 192
#define WW 192
#define SS 6                 // rows per block strip  (HH/SS = 32 strips)
#define NPIX (SS*WW)         // 1152 pixels per block
#define NBPIX (BB*HH*WW)     // 294912
#define NT 512
#define NW (NT/64)           // 8 waves
#define CPW (CC/NW)          // 10 channels per wave

__global__ __launch_bounds__(NT, 2) void fused_kernel(const float* __restrict__ heat,
                                                      const float* __restrict__ box,
                                                      float* __restrict__ out) {
    const int tid  = threadIdx.x;
    const int lane = tid & 63;
    const int wv   = tid >> 6;        // wave 0..7
    const int yt   = blockIdx.x;      // 0..31
    const int b    = blockIdx.y;      // 0..7
    const int y0   = yt * SS;
    const bool lok = lane < 48;
    const int  col0 = lane * 4;

    __shared__ float red[NW][SS][WW]; // 36 KB

    float4 sc[SS];
#pragma unroll
    for (int i = 0; i < SS; ++i) sc[i] = make_float4(0.f, 0.f, 0.f, 0.f);

    const int cbase = wv * CPW;
    const float NI = -INFINITY;

    // channel load: 8 rows (strip + vertical halo) of float4 per lane
#define LOADCH(V, CH) {                                                        \
        const float* hp = heat + ((size_t)(b * CC + (CH)) * HH) * WW;          \
        _Pragma("unroll")                                                      \
        for (int r = 0; r < SS + 2; ++r) {                                     \
            const int  row = y0 - 1 + r;                                       \
            const bool ok  = lok && ((unsigned)row < HH);                      \
            V[r] = ok ? *reinterpret_cast<const float4*>(hp + row * WW + col0) \
                      : make_float4(NI, NI, NI, NI);                           \
        } }

    // 3x3 NMS + running channel-max into sc
#define COMPUTECH(V) {                                                         \
        _Pragma("unroll")                                                      \
        for (int i = 0; i < SS; ++i) {                                         \
            const float4 a = V[i], m = V[i + 1], d = V[i + 2];                 \
            float4 vm;                                                         \
            vm.x = fmaxf(fmaxf(a.x, m.x), d.x);                                \
            vm.y = fmaxf(fmaxf(a.y, m.y), d.y);                                \
            vm.z = fmaxf(fmaxf(a.z, m.z), d.z);                                \
            vm.w = fmaxf(fmaxf(a.w, m.w), d.w);                                \
            float L = __shfl_up(vm.w, 1);                                      \
            float R = __shfl_down(vm.x, 1);                                    \
            if (lane == 0)  L = NI;                                            \
            if (lane >= 47) R = NI;                                            \
            float4 hm;                                                         \
            hm.x = fmaxf(fmaxf(L,    vm.x), vm.y);                             \
            hm.y = fmaxf(fmaxf(vm.x, vm.y), vm.z);                             \
            hm.z = fmaxf(fmaxf(vm.y, vm.z), vm.w);                             \
            hm.w = fmaxf(fmaxf(vm.z, vm.w), R);                                \
            sc[i].x = fmaxf(sc[i].x, (m.x == hm.x) ? m.x : 0.0f);              \
            sc[i].y = fmaxf(sc[i].y, (m.y == hm.y) ? m.y : 0.0f);              \
            sc[i].z = fmaxf(sc[i].z, (m.z == hm.z) ? m.z : 0.0f);              \
            sc[i].w = fmaxf(sc[i].w, (m.w == hm.w) ? m.w : 0.0f);              \
        } }

    float4 va[SS + 2], vb[SS + 2];
    LOADCH(va, cbase);                       // prologue: channel 0 in flight
#pragma unroll
    for (int k = 0; k < CPW; k += 2) {       // CPW=10, even
        LOADCH(vb, cbase + k + 1);           // issue k+1 while k computes
        COMPUTECH(va);
        if (k + 2 < CPW) LOADCH(va, cbase + k + 2);  // issue k+2 while k+1 computes
        COMPUTECH(vb);
    }

    // ---- decode prefetch: issue box loads BEFORE the barrier (latency hides
    //      under barrier + LDS reduce). Strip is linear: pix = pixbase + idx.
    const int    pixbase = (b * HH + y0) * WW;
    const float* bp0     = box + (size_t)b * 4 * HH * WW + (size_t)y0 * WW;
    float pdx[3], pdy[3], pw[3], ph[3];
#pragma unroll
    for (int kk = 0; kk < 3; ++kk) {
        const int idx = kk * NT + tid;
        if (idx < NPIX) {
            pdx[kk] = bp0[idx];
            pdy[kk] = bp0[idx + (size_t)HH * WW];
            pw[kk]  = bp0[idx + (size_t)2 * HH * WW];
            ph[kk]  = bp0[idx + (size_t)3 * HH * WW];
        }
    }

    if (lok) {
#pragma unroll
        for (int i = 0; i < SS; ++i)
            *reinterpret_cast<float4*>(&red[wv][i][col0]) = sc[i];
    }
    __syncthreads();

    float* boxes  = out;
    float* maskp  = out + (size_t)4 * NBPIX;
    float* scorep = out + (size_t)5 * NBPIX;
    float* ctr    = out + (size_t)6 * NBPIX;

    const float* rf = &red[0][0][0];      // linear view: rf[w*NPIX + idx]

#pragma unroll
    for (int kk = 0; kk < 3; ++kk) {
        const int idx = kk * NT + tid;
        if (idx < NPIX) {
            const int row = idx / WW;
            const int x   = idx - row * WW;
            const int y   = y0 + row;

            float s = rf[idx];
#pragma unroll
            for (int w = 1; w < NW; ++w) s = fmaxf(s, rf[w * NPIX + idx]);
            const bool m = s > 0.7f;

            const float cx = ((float)x + pdx[kk]) * 4.0f;
            const float cy = ((float)y + pdy[kk]) * 4.0f;
            const float w4 = pw[kk] * 4.0f;
            const float h4 = ph[kk] * 4.0f;
            const float lim = 768.0f;
            const float x1 = fminf(fmaxf(cx - w4 * 0.5f, 0.0f), lim);
            const float y1 = fminf(fmaxf(cy - h4 * 0.5f, 0.0f), lim);
            const float x2 = fminf(fmaxf(cx + w4 * 0.5f, 0.0f), lim);
            const float y2 = fminf(fmaxf(cy + h4 * 0.5f, 0.0f), lim);

            const int pix = pixbase + idx;

            float4 bo;
            bo.x = m ? x1 : 0.0f;
            bo.y = m ? y1 : 0.0f;
            bo.z = m ? (x2 - x1) : 0.0f;
            bo.w = m ? (y2 - y1) : 0.0f;
            reinterpret_cast<float4*>(boxes)[pix] = bo;

            maskp[pix]  = m ? 1.0f : 0.0f;
            scorep[pix] = m ? s : 0.0f;

            float2 cc;
            cc.x = m ? cx : 0.0f;
            cc.y = m ? cy : 0.0f;
            reinterpret_cast<float2*>(ctr)[pix] = cc;
        }
    }
}

extern "C" void kernel_launch(void* const* d_in, const int* in_sizes, int n_in,
                              void* d_out, int out_size, void* d_ws, size_t ws_size,
                              hipStream_t stream) {
    const float* heat = (const float*)d_in[0];
    const float* box  = (const float*)d_in[1];
    float* out = (float*)d_out;

    dim3 g(HH / SS, BB);              // 32 x 8 = 256 blocks, 1 per CU
    fused_kernel<<<g, NT, 0, stream>>>(heat, box, out);
}

// Round 5
// 145.278 us; speedup vs baseline: 1.9304x; 1.9003x over previous
//
#include <hip/hip_runtime.h>
#include <math.h>

// CenterNetDecode fused: heat [8,80,192,192] f32, box [8,4,192,192] f32
// outputs (flat concat): boxes [B,H,W,4], mask [B,H,W], scores [B,H,W], center [B,H,W,2]
//
// Single kernel, 512 threads = 8 waves, float4 / 48-lane row layout,
// SINGLE-buffered channel loop (v[8]). This is the round-1 structure, which
// is proven spill-free: the 2-deep pipelined variants (rounds 3/4) need
// ~150 VGPRs but hipcc pins the cap at 128 regardless of __launch_bounds__
// second arg, spilling everything to scratch (WRITE_SIZE 191 MB vs 9.4
// ideal, kernel 182us). Do NOT add register double-buffering here without
// first verifying VGPR_Count > 128 is attainable.
//
// NEW vs round 1: batch->XCD swizzle. Grid is linear 256 blocks with
// b = id & 7, yt = id >> 3, so (XCD = linear id % 8) == batch. All 32
// row-strips of a batch run on one XCD's 32 CUs in channel lockstep
// (~1.2 MB concurrent heat working set << 4 MB L2), so the 2-row vertical
// halo every strip re-reads (25% of heat = ~31 MB) becomes L2 hits instead
// of HBM traffic. With the old (yt,b) grid, XCD = yt % 8 put adjacent
// strips on DIFFERENT XCDs: round-2 counters showed FETCH 125 MB = the
// zero-absorption prediction.

#define BB 8
#define CC 80
#define HH 192
#define WW 192
#define SS 6                 // rows per block strip  (HH/SS = 32 strips)
#define NPIX (SS*WW)         // 1152 pixels per block
#define NBPIX (BB*HH*WW)     // 294912
#define NT 512
#define NW (NT/64)           // 8 waves
#define CPW (CC/NW)          // 10 channels per wave

__global__ __launch_bounds__(NT) void fused_kernel(const float* __restrict__ heat,
                                                   const float* __restrict__ box,
                                                   float* __restrict__ out) {
    const int tid  = threadIdx.x;
    const int lane = tid & 63;
    const int wv   = tid >> 6;        // wave 0..7
    const int bid  = blockIdx.x;      // 0..255 linear
    const int b    = bid & 7;         // XCD = bid % 8 == batch
    const int yt   = bid >> 3;        // 0..31 strip
    const int y0   = yt * SS;
    const bool lok = lane < 48;
    const int  col0 = lane * 4;

    __shared__ float red[NW][SS][WW]; // 36 KB

    float4 sc[SS];
#pragma unroll
    for (int i = 0; i < SS; ++i) sc[i] = make_float4(0.f, 0.f, 0.f, 0.f);

    const int cbase = wv * CPW;
    const float NI = -INFINITY;

    for (int k = 0; k < CPW; ++k) {
        const int c = cbase + k;
        const float* hp = heat + ((size_t)(b * CC + c) * HH) * WW;
        float4 v[SS + 2];
#pragma unroll
        for (int r = 0; r < SS + 2; ++r) {
            const int  row = y0 - 1 + r;
            const bool ok  = lok && ((unsigned)row < HH);
            v[r] = ok ? *reinterpret_cast<const float4*>(hp + row * WW + col0)
                      : make_float4(NI, NI, NI, NI);
        }
#pragma unroll
        for (int i = 0; i < SS; ++i) {
            const float4 a = v[i], m = v[i + 1], d = v[i + 2];
            float4 vm;
            vm.x = fmaxf(fmaxf(a.x, m.x), d.x);
            vm.y = fmaxf(fmaxf(a.y, m.y), d.y);
            vm.z = fmaxf(fmaxf(a.z, m.z), d.z);
            vm.w = fmaxf(fmaxf(a.w, m.w), d.w);

            float L = __shfl_up(vm.w, 1);    // left neighbor's col (4l-1)
            float R = __shfl_down(vm.x, 1);  // right neighbor's col (4l+4)
            if (lane == 0)  L = NI;          // image left edge
            if (lane >= 47) R = NI;          // image right edge / inactive

            float4 hm;
            hm.x = fmaxf(fmaxf(L,    vm.x), vm.y);
            hm.y = fmaxf(fmaxf(vm.x, vm.y), vm.z);
            hm.z = fmaxf(fmaxf(vm.y, vm.z), vm.w);
            hm.w = fmaxf(fmaxf(vm.z, vm.w), R);

            sc[i].x = fmaxf(sc[i].x, (m.x == hm.x) ? m.x : 0.0f);
            sc[i].y = fmaxf(sc[i].y, (m.y == hm.y) ? m.y : 0.0f);
            sc[i].z = fmaxf(sc[i].z, (m.z == hm.z) ? m.z : 0.0f);
            sc[i].w = fmaxf(sc[i].w, (m.w == hm.w) ? m.w : 0.0f);
        }
    }

    // ---- decode prefetch: issue box loads BEFORE the barrier (latency hides
    //      under barrier + LDS reduce). Strip is linear: pix = pixbase + idx.
    const int    pixbase = (b * HH + y0) * WW;
    const float* bp0     = box + (size_t)b * 4 * HH * WW + (size_t)y0 * WW;
    float pdx[3], pdy[3], pw[3], ph[3];
#pragma unroll
    for (int kk = 0; kk < 3; ++kk) {
        const int idx = kk * NT + tid;
        if (idx < NPIX) {
            pdx[kk] = bp0[idx];
            pdy[kk] = bp0[idx + (size_t)HH * WW];
            pw[kk]  = bp0[idx + (size_t)2 * HH * WW];
            ph[kk]  = bp0[idx + (size_t)3 * HH * WW];
        }
    }

    if (lok) {
#pragma unroll
        for (int i = 0; i < SS; ++i)
            *reinterpret_cast<float4*>(&red[wv][i][col0]) = sc[i];
    }
    __syncthreads();

    float* boxes  = out;
    float* maskp  = out + (size_t)4 * NBPIX;
    float* scorep = out + (size_t)5 * NBPIX;
    float* ctr    = out + (size_t)6 * NBPIX;

    const float* rf = &red[0][0][0];      // linear view: rf[w*NPIX + idx]

#pragma unroll
    for (int kk = 0; kk < 3; ++kk) {
        const int idx = kk * NT + tid;
        if (idx < NPIX) {
            const int row = idx / WW;
            const int x   = idx - row * WW;
            const int y   = y0 + row;

            float s = rf[idx];
#pragma unroll
            for (int w = 1; w < NW; ++w) s = fmaxf(s, rf[w * NPIX + idx]);
            const bool m = s > 0.7f;

            const float cx = ((float)x + pdx[kk]) * 4.0f;
            const float cy = ((float)y + pdy[kk]) * 4.0f;
            const float w4 = pw[kk] * 4.0f;
            const float h4 = ph[kk] * 4.0f;
            const float lim = 768.0f;
            const float x1 = fminf(fmaxf(cx - w4 * 0.5f, 0.0f), lim);
            const float y1 = fminf(fmaxf(cy - h4 * 0.5f, 0.0f), lim);
            const float x2 = fminf(fmaxf(cx + w4 * 0.5f, 0.0f), lim);
            const float y2 = fminf(fmaxf(cy + h4 * 0.5f, 0.0f), lim);

            const int pix = pixbase + idx;

            float4 bo;
            bo.x = m ? x1 : 0.0f;
            bo.y = m ? y1 : 0.0f;
            bo.z = m ? (x2 - x1) : 0.0f;
            bo.w = m ? (y2 - y1) : 0.0f;
            reinterpret_cast<float4*>(boxes)[pix] = bo;

            maskp[pix]  = m ? 1.0f : 0.0f;
            scorep[pix] = m ? s : 0.0f;

            float2 cc;
            cc.x = m ? cx : 0.0f;
            cc.y = m ? cy : 0.0f;
            reinterpret_cast<float2*>(ctr)[pix] = cc;
        }
    }
}

extern "C" void kernel_launch(void* const* d_in, const int* in_sizes, int n_in,
                              void* d_out, int out_size, void* d_ws, size_t ws_size,
                              hipStream_t stream) {
    const float* heat = (const float*)d_in[0];
    const float* box  = (const float*)d_in[1];
    float* out = (float*)d_out;

    fused_kernel<<<dim3(256), NT, 0, stream>>>(heat, box, out);
}

// Round 6
// 144.363 us; speedup vs baseline: 1.9426x; 1.0063x over previous
//
#include <hip/hip_runtime.h>
#include <math.h>

// CenterNetDecode fused: heat [8,80,192,192] f32, box [8,4,192,192] f32
// outputs (flat concat): boxes [B,H,W,4], mask [B,H,W], scores [B,H,W], center [B,H,W,2]
//
// Single kernel, 512 threads = 8 waves, float4 / 48-lane row layout,
// SINGLE-buffered channel loop. REGISTER RULE (rounds 2-4): this kernel's
// VGPR cap is 128 no matter what __launch_bounds__ says; any variant needing
// more (reg double-buffering) spills catastrophically (WRITE_SIZE 191 MB vs
// 9.4 ideal, 182us). All latency hiding must be register-free.
//
// SS=3 (was 6): grid = 64 strips x 8 batches = 512 blocks = exactly 2
// blocks/CU -> 4 waves/SIMD. Rationale: with 1 block/CU the 8 lockstep waves
// alternate {issue 6KB of loads, drain, compute ~600cy} leaving VMEM idle
// ~40% of the time (33us observed vs 21us BW floor). Doubling resident waves
// (and desynced blocks) keeps loads in flight during other waves' compute.
// Register state DROPS (v[5]+sc[3]) -> no spill risk. Halo ratio rises to
// 5/3, but batch->XCD swizzle (b = bid&7: one batch per XCD, channel
// lockstep, ~0.6 MB working set << 4 MB L2) makes halo re-reads L2 hits.

#define BB 8
#define CC 80
#define HH 192
#define WW 192
#define SS 3                 // rows per block strip  (HH/SS = 64 strips)
#define NPIX (SS*WW)         // 576 pixels per block
#define NBPIX (BB*HH*WW)     // 294912
#define NT 512
#define NW (NT/64)           // 8 waves
#define CPW (CC/NW)          // 10 channels per wave

__global__ __launch_bounds__(NT) void fused_kernel(const float* __restrict__ heat,
                                                   const float* __restrict__ box,
                                                   float* __restrict__ out) {
    const int tid  = threadIdx.x;
    const int lane = tid & 63;
    const int wv   = tid >> 6;        // wave 0..7
    const int bid  = blockIdx.x;      // 0..511 linear
    const int b    = bid & 7;         // XCD = bid % 8 == batch
    const int yt   = bid >> 3;        // 0..63 strip
    const int y0   = yt * SS;
    const bool lok = lane < 48;
    const int  col0 = lane * 4;

    __shared__ float red[NW][SS][WW]; // 18 KB -> 2 blocks/CU co-resident

    float4 sc[SS];
#pragma unroll
    for (int i = 0; i < SS; ++i) sc[i] = make_float4(0.f, 0.f, 0.f, 0.f);

    const int cbase = wv * CPW;
    const float NI = -INFINITY;

    for (int k = 0; k < CPW; ++k) {
        const int c = cbase + k;
        const float* hp = heat + ((size_t)(b * CC + c) * HH) * WW;
        float4 v[SS + 2];
#pragma unroll
        for (int r = 0; r < SS + 2; ++r) {
            const int  row = y0 - 1 + r;
            const bool ok  = lok && ((unsigned)row < HH);
            v[r] = ok ? *reinterpret_cast<const float4*>(hp + row * WW + col0)
                      : make_float4(NI, NI, NI, NI);
        }
#pragma unroll
        for (int i = 0; i < SS; ++i) {
            const float4 a = v[i], m = v[i + 1], d = v[i + 2];
            float4 vm;
            vm.x = fmaxf(fmaxf(a.x, m.x), d.x);
            vm.y = fmaxf(fmaxf(a.y, m.y), d.y);
            vm.z = fmaxf(fmaxf(a.z, m.z), d.z);
            vm.w = fmaxf(fmaxf(a.w, m.w), d.w);

            float L = __shfl_up(vm.w, 1);    // left neighbor's col (4l-1)
            float R = __shfl_down(vm.x, 1);  // right neighbor's col (4l+4)
            if (lane == 0)  L = NI;          // image left edge
            if (lane >= 47) R = NI;          // image right edge / inactive

            float4 hm;
            hm.x = fmaxf(fmaxf(L,    vm.x), vm.y);
            hm.y = fmaxf(fmaxf(vm.x, vm.y), vm.z);
            hm.z = fmaxf(fmaxf(vm.y, vm.z), vm.w);
            hm.w = fmaxf(fmaxf(vm.z, vm.w), R);

            sc[i].x = fmaxf(sc[i].x, (m.x == hm.x) ? m.x : 0.0f);
            sc[i].y = fmaxf(sc[i].y, (m.y == hm.y) ? m.y : 0.0f);
            sc[i].z = fmaxf(sc[i].z, (m.z == hm.z) ? m.z : 0.0f);
            sc[i].w = fmaxf(sc[i].w, (m.w == hm.w) ? m.w : 0.0f);
        }
    }

    // ---- decode prefetch: issue box loads BEFORE the barrier (latency hides
    //      under barrier + LDS reduce). Strip is linear: pix = pixbase + idx.
    const int    pixbase = (b * HH + y0) * WW;
    const float* bp0     = box + (size_t)b * 4 * HH * WW + (size_t)y0 * WW;
    float pdx[2], pdy[2], pw[2], ph[2];
#pragma unroll
    for (int kk = 0; kk < 2; ++kk) {
        const int idx = kk * NT + tid;
        if (idx < NPIX) {
            pdx[kk] = bp0[idx];
            pdy[kk] = bp0[idx + (size_t)HH * WW];
            pw[kk]  = bp0[idx + (size_t)2 * HH * WW];
            ph[kk]  = bp0[idx + (size_t)3 * HH * WW];
        }
    }

    if (lok) {
#pragma unroll
        for (int i = 0; i < SS; ++i)
            *reinterpret_cast<float4*>(&red[wv][i][col0]) = sc[i];
    }
    __syncthreads();

    float* boxes  = out;
    float* maskp  = out + (size_t)4 * NBPIX;
    float* scorep = out + (size_t)5 * NBPIX;
    float* ctr    = out + (size_t)6 * NBPIX;

    const float* rf = &red[0][0][0];      // linear view: rf[w*NPIX + idx]

#pragma unroll
    for (int kk = 0; kk < 2; ++kk) {
        const int idx = kk * NT + tid;
        if (idx < NPIX) {
            const int row = idx / WW;
            const int x   = idx - row * WW;
            const int y   = y0 + row;

            float s = rf[idx];
#pragma unroll
            for (int w = 1; w < NW; ++w) s = fmaxf(s, rf[w * NPIX + idx]);
            const bool m = s > 0.7f;

            const float cx = ((float)x + pdx[kk]) * 4.0f;
            const float cy = ((float)y + pdy[kk]) * 4.0f;
            const float w4 = pw[kk] * 4.0f;
            const float h4 = ph[kk] * 4.0f;
            const float lim = 768.0f;
            const float x1 = fminf(fmaxf(cx - w4 * 0.5f, 0.0f), lim);
            const float y1 = fminf(fmaxf(cy - h4 * 0.5f, 0.0f), lim);
            const float x2 = fminf(fmaxf(cx + w4 * 0.5f, 0.0f), lim);
            const float y2 = fminf(fmaxf(cy + h4 * 0.5f, 0.0f), lim);

            const int pix = pixbase + idx;

            float4 bo;
            bo.x = m ? x1 : 0.0f;
            bo.y = m ? y1 : 0.0f;
            bo.z = m ? (x2 - x1) : 0.0f;
            bo.w = m ? (y2 - y1) : 0.0f;
            reinterpret_cast<float4*>(boxes)[pix] = bo;

            maskp[pix]  = m ? 1.0f : 0.0f;
            scorep[pix] = m ? s : 0.0f;

            float2 cc;
            cc.x = m ? cx : 0.0f;
            cc.y = m ? cy : 0.0f;
            reinterpret_cast<float2*>(ctr)[pix] = cc;
        }
    }
}

extern "C" void kernel_launch(void* const* d_in, const int* in_sizes, int n_in,
                              void* d_out, int out_size, void* d_ws, size_t ws_size,
                              hipStream_t stream) {
    const float* heat = (const float*)d_in[0];
    const float* box  = (const float*)d_in[1];
    float* out = (float*)d_out;

    fused_kernel<<<dim3((HH / SS) * BB), NT, 0, stream>>>(heat, box, out);
}